// Round 1
// baseline (223.735 us; speedup 1.0000x reference)
//
#include <hip/hip_runtime.h>

// Problem constants
#define B_DIM 32
#define V_DIM 21
#define D_DIM 512
#define P_DIM 64
#define M_TOTAL 672          // B*V
#define K_TOTAL 32768        // D*P
#define OUT_DIM 96
#define E_DIM 8
#define R_DIM 8
#define H_DIM 256
#define N_TOTAL 160          // OUT_DIM + E*R
#define SCALING 2.0f

// GEMM tiling
#define BM 64
#define BK 128
#define KSPLIT 32
#define K_PER_BLOCK (K_TOTAL / KSPLIT)   // 1024
#define CHUNKS (K_PER_BLOCK / BK)        // 8
#define LDS_K (BK + 8)                   // +16B pad: fragment reads 2-way bank alias (free)

typedef __attribute__((ext_vector_type(4))) float floatx4;
typedef __attribute__((ext_vector_type(8))) short short8;

__device__ __forceinline__ unsigned short f2bf(float f) {
  union { float f; unsigned int u; } v; v.f = f;
  unsigned int u = v.u + (0x7FFFu + ((v.u >> 16) & 1u));  // RNE
  return (unsigned short)(u >> 16);
}

// ---------------- pooling: pooled[b,d] = mean over (v,p) of x[b,v,d,p] -------
__global__ __launch_bounds__(256) void pool_kernel(const float* __restrict__ x,
                                                   float* __restrict__ pooled) {
  int wid = blockIdx.x * 4 + (threadIdx.x >> 6);   // 0..16383 = b*512+d
  int lane = threadIdx.x & 63;
  int b = wid >> 9;
  int d = wid & 511;
  const float* base = x + (((size_t)b * V_DIM) * D_DIM + d) * P_DIM + lane;
  float s = 0.0f;
  #pragma unroll
  for (int v = 0; v < V_DIM; ++v) s += base[(size_t)v * D_DIM * P_DIM];
  #pragma unroll
  for (int off = 32; off > 0; off >>= 1) s += __shfl_down(s, off, 64);
  if (lane == 0) pooled[wid] = s * (1.0f / (V_DIM * (float)P_DIM));
}

// ---------------- fused base+LoRA GEMM: S[672,160] += flat @ [W_base|lora_A]^T
__global__ __launch_bounds__(256, 2)
void gemm_kernel(const float* __restrict__ x, const float* __restrict__ W_base,
                 const float* __restrict__ lora_A, float* __restrict__ S) {
  __shared__ short ldsA[BM * LDS_K];      // 17,408 B
  __shared__ short ldsW[N_TOTAL * LDS_K]; // 43,520 B
  const int tid = threadIdx.x;
  const int m0 = blockIdx.x * BM;
  const int kbase = blockIdx.y * K_PER_BLOCK;
  const int lane = tid & 63;
  const int wave = tid >> 6;
  const int quad = lane >> 4;
  const int l16 = lane & 15;

  floatx4 acc[10];
  #pragma unroll
  for (int i = 0; i < 10; ++i) acc[i] = (floatx4)(0.0f);

  for (int c = 0; c < CHUNKS; ++c) {
    const int kc = kbase + c * BK;
    __syncthreads();
    // stage A tile: 64 rows x 128 k (groups of 8 floats -> 8 bf16 = 16B LDS write)
    #pragma unroll
    for (int it = 0; it < 4; ++it) {
      int idx = it * 256 + tid;
      int row = idx >> 4;
      int g = idx & 15;
      int m = m0 + row;
      float vals[8];
      if (m < M_TOTAL) {
        const floatx4* s4 = (const floatx4*)(x + (size_t)m * K_TOTAL + kc + g * 8);
        floatx4 v0 = s4[0], v1 = s4[1];
        vals[0] = v0[0]; vals[1] = v0[1]; vals[2] = v0[2]; vals[3] = v0[3];
        vals[4] = v1[0]; vals[5] = v1[1]; vals[6] = v1[2]; vals[7] = v1[3];
      } else {
        #pragma unroll
        for (int j = 0; j < 8; ++j) vals[j] = 0.0f;
      }
      short8 sv;
      #pragma unroll
      for (int j = 0; j < 8; ++j) sv[j] = (short)f2bf(vals[j]);
      *(short8*)&ldsA[row * LDS_K + g * 8] = sv;
    }
    // stage W tile: 160 rows x 128 k (rows 0..95 = W_base, 96..159 = lora_A)
    #pragma unroll
    for (int it = 0; it < 10; ++it) {
      int idx = it * 256 + tid;
      int row = idx >> 4;
      int g = idx & 15;
      const float* rowp = (row < OUT_DIM) ? (W_base + (size_t)row * K_TOTAL)
                                          : (lora_A + (size_t)(row - OUT_DIM) * K_TOTAL);
      const floatx4* s4 = (const floatx4*)(rowp + kc + g * 8);
      floatx4 v0 = s4[0], v1 = s4[1];
      short8 sv;
      sv[0] = (short)f2bf(v0[0]); sv[1] = (short)f2bf(v0[1]);
      sv[2] = (short)f2bf(v0[2]); sv[3] = (short)f2bf(v0[3]);
      sv[4] = (short)f2bf(v1[0]); sv[5] = (short)f2bf(v1[1]);
      sv[6] = (short)f2bf(v1[2]); sv[7] = (short)f2bf(v1[3]);
      *(short8*)&ldsW[row * LDS_K + g * 8] = sv;
    }
    __syncthreads();
    // MFMA: wave handles rows [wave*16, wave*16+16), all 160 cols
    #pragma unroll
    for (int ks = 0; ks < 4; ++ks) {
      const int ko = ks * 32 + quad * 8;
      short8 a = *(const short8*)&ldsA[(wave * 16 + l16) * LDS_K + ko];
      #pragma unroll
      for (int nt = 0; nt < 10; ++nt) {
        short8 b = *(const short8*)&ldsW[(nt * 16 + l16) * LDS_K + ko];
        acc[nt] = __builtin_amdgcn_mfma_f32_16x16x32_bf16(a, b, acc[nt], 0, 0, 0);
      }
    }
  }
  // split-K accumulate (D layout: col=lane&15, row=quad*4+reg)
  #pragma unroll
  for (int nt = 0; nt < 10; ++nt) {
    #pragma unroll
    for (int r = 0; r < 4; ++r) {
      int m = m0 + wave * 16 + quad * 4 + r;
      int n = nt * 16 + l16;
      if (m < M_TOTAL) atomicAdd(&S[(size_t)m * N_TOTAL + n], acc[nt][r]);
    }
  }
}

// ---------------- router: MLP + softmax + top-2 ------------------------------
__global__ __launch_bounds__(256)
void router_kernel(const float* __restrict__ pooled, const float* __restrict__ W1,
                   const float* __restrict__ b1, const float* __restrict__ W2,
                   const float* __restrict__ b2, float* __restrict__ wfull,
                   float* __restrict__ probs_out) {
  __shared__ float sp[D_DIM];
  __shared__ float sh[H_DIM];
  __shared__ float slog[E_DIM];
  const int b = blockIdx.x;
  const int t = threadIdx.x;
  sp[t] = pooled[b * D_DIM + t];
  sp[t + 256] = pooled[b * D_DIM + t + 256];
  __syncthreads();
  float acc = b1[t];
  const float* w1r = W1 + (size_t)t * D_DIM;
  for (int d = 0; d < D_DIM; ++d) acc += sp[d] * w1r[d];
  sh[t] = fmaxf(acc, 0.0f);
  __syncthreads();
  if (t < E_DIM) {
    float a = b2[t];
    const float* w2r = W2 + t * H_DIM;
    for (int j = 0; j < H_DIM; ++j) a += sh[j] * w2r[j];
    slog[t] = a;
  }
  __syncthreads();
  if (t == 0) {
    float p[E_DIM];
    float mx = slog[0];
    for (int e = 1; e < E_DIM; ++e) mx = fmaxf(mx, slog[e]);
    float se = 0.0f;
    for (int e = 0; e < E_DIM; ++e) { p[e] = __expf(slog[e] - mx); se += p[e]; }
    float inv = 1.0f / se;
    for (int e = 0; e < E_DIM; ++e) { p[e] *= inv; probs_out[b * E_DIM + e] = p[e]; }
    // top-2, lowest index wins ties (strict > keeps earlier index)
    int i0 = 0;
    for (int e = 1; e < E_DIM; ++e) if (p[e] > p[i0]) i0 = e;
    int i1 = (i0 == 0) ? 1 : 0;
    for (int e = 0; e < E_DIM; ++e) if (e != i0 && p[e] > p[i1]) i1 = e;
    float s2 = p[i0] + p[i1];
    float invs = 1.0f / fmaxf(s2, 1e-6f);
    for (int e = 0; e < E_DIM; ++e) {
      float w = 0.0f;
      if (e == i0) w += p[i0] * invs;
      if (e == i1) w += p[i1] * invs;
      wfull[b * E_DIM + e] = w;
    }
  }
}

// ---------------- combine: out = S_base + b_base + 2*sum_e w*(S_lora.lora_B) -
__global__ __launch_bounds__(256)
void combine_kernel(const float* __restrict__ S, const float* __restrict__ b_base,
                    const float* __restrict__ lora_B, const float* __restrict__ wfull,
                    float* __restrict__ out) {
  int idx = blockIdx.x * 256 + threadIdx.x;
  if (idx >= M_TOTAL * OUT_DIM) return;
  int bv = idx / OUT_DIM;
  int o = idx - bv * OUT_DIM;
  int b = bv / V_DIM;
  const float* srow = S + (size_t)bv * N_TOTAL;
  float base = srow[o] + b_base[o];
  float moe = 0.0f;
  #pragma unroll
  for (int e = 0; e < E_DIM; ++e) {
    float we = wfull[b * E_DIM + e];
    if (we != 0.0f) {
      const float* lb = lora_B + ((size_t)e * OUT_DIM + o) * R_DIM;
      const float* tr = srow + OUT_DIM + e * R_DIM;
      float d = 0.0f;
      #pragma unroll
      for (int r = 0; r < R_DIM; ++r) d += tr[r] * lb[r];
      moe += we * d;
    }
  }
  out[idx] = base + SCALING * moe;
}

extern "C" void kernel_launch(void* const* d_in, const int* in_sizes, int n_in,
                              void* d_out, int out_size, void* d_ws, size_t ws_size,
                              hipStream_t stream) {
  const float* x      = (const float*)d_in[0];
  const float* W_base = (const float*)d_in[1];
  const float* b_base = (const float*)d_in[2];
  const float* W1     = (const float*)d_in[3];
  const float* b1     = (const float*)d_in[4];
  const float* W2     = (const float*)d_in[5];
  const float* b2     = (const float*)d_in[6];
  const float* lora_A = (const float*)d_in[7];
  const float* lora_B = (const float*)d_in[8];
  float* out = (float*)d_out;

  // workspace layout (floats): pooled[16384] | S[672*160] | wfull[256]
  float* ws     = (float*)d_ws;
  float* pooled = ws;
  float* S      = ws + 16384;
  float* wfull  = ws + 16384 + (size_t)M_TOTAL * N_TOTAL;

  // zero pooled + S (harness poisons ws with 0xAA every launch)
  hipMemsetAsync(d_ws, 0, (16384 + (size_t)M_TOTAL * N_TOTAL) * sizeof(float), stream);

  pool_kernel<<<4096, 256, 0, stream>>>(x, pooled);
  gemm_kernel<<<dim3(11, KSPLIT), 256, 0, stream>>>(x, W_base, lora_A, S);
  router_kernel<<<B_DIM, 256, 0, stream>>>(pooled, W1, b1, W2, b2, wfull,
                                           out + (size_t)M_TOTAL * OUT_DIM);
  combine_kernel<<<(M_TOTAL * OUT_DIM + 255) / 256, 256, 0, stream>>>(
      S, b_base, lora_B, wfull, out);
}

// Round 2
// 219.972 us; speedup vs baseline: 1.0171x; 1.0171x over previous
//
#include <hip/hip_runtime.h>

// Problem constants
#define B_DIM 32
#define V_DIM 21
#define D_DIM 512
#define P_DIM 64
#define M_TOTAL 672          // B*V
#define K_TOTAL 32768        // D*P
#define OUT_DIM 96
#define E_DIM 8
#define R_DIM 8
#define H_DIM 256
#define N_TOTAL 160          // OUT_DIM + E*R
#define SCALING 2.0f
#define POOL_SCALE (1.0f / (V_DIM * (float)P_DIM))

// GEMM tiling
#define BM 64
#define BK 128
#define KSPLIT 32
#define K_PER_BLOCK (K_TOTAL / KSPLIT)   // 1024
#define CHUNKS (K_PER_BLOCK / BK)        // 8
#define LDS_K (BK + 8)                   // +16B pad: fragment reads 2-way bank alias (free)

typedef __attribute__((ext_vector_type(4))) float floatx4;
typedef __attribute__((ext_vector_type(8))) short short8;

__device__ __forceinline__ unsigned short f2bf(float f) {
  union { float f; unsigned int u; } v; v.f = f;
  unsigned int u = v.u + (0x7FFFu + ((v.u >> 16) & 1u));  // RNE
  return (unsigned short)(u >> 16);
}

// ---------------- fused base+LoRA GEMM + router pooling ----------------------
// S[672,160] += flat @ [W_base|lora_A]^T ; pooled[b,d] += partial sums of x
__global__ __launch_bounds__(256, 2)
void gemm_kernel(const float* __restrict__ x, const float* __restrict__ W_base,
                 const float* __restrict__ lora_A, float* __restrict__ S,
                 float* __restrict__ pooled) {
  __shared__ short ldsA[BM * LDS_K];      // 17,408 B
  __shared__ short ldsW[N_TOTAL * LDS_K]; // 43,520 B
  __shared__ float lds_pool[5 * 16];      // [b_local][d_local] fp32 partial sums
  const int tid = threadIdx.x;
  const int m0 = blockIdx.x * BM;
  const int kbase = blockIdx.y * K_PER_BLOCK;
  const int lane = tid & 63;
  const int wave = tid >> 6;
  const int quad = lane >> 4;
  const int l16 = lane & 15;
  const int b_first = m0 / V_DIM;
  const int d_first = kbase >> 6;   // k = d*64 + p

  if (tid < 80) lds_pool[tid] = 0.0f;

  floatx4 acc[10];
  #pragma unroll
  for (int i = 0; i < 10; ++i) acc[i] = (floatx4)(0.0f);

  for (int c = 0; c < CHUNKS; ++c) {
    const int kc = kbase + c * BK;
    __syncthreads();   // protects prev iter's LDS reads; 1st iter: lds_pool zero
    // stage A tile: 64 rows x 128 k (8 floats -> 8 bf16 = 16B LDS write)
    #pragma unroll
    for (int it = 0; it < 4; ++it) {
      int idx = it * 256 + tid;
      int row = idx >> 4;
      int g = idx & 15;
      int m = m0 + row;
      float vals[8];
      if (m < M_TOTAL) {
        const floatx4* s4 = (const floatx4*)(x + (size_t)m * K_TOTAL + kc + g * 8);
        floatx4 v0 = s4[0], v1 = s4[1];
        vals[0] = v0[0]; vals[1] = v0[1]; vals[2] = v0[2]; vals[3] = v0[3];
        vals[4] = v1[0]; vals[5] = v1[1]; vals[6] = v1[2]; vals[7] = v1[3];
        // fused pooling: all 8 vals share one d (8 consec k within a 64-k d-run)
        float sum8 = (vals[0] + vals[1]) + (vals[2] + vals[3]) +
                     ((vals[4] + vals[5]) + (vals[6] + vals[7]));
        int b_local = (m / V_DIM) - b_first;
        int d_local = ((kc + g * 8) >> 6) - d_first;
        atomicAdd(&lds_pool[b_local * 16 + d_local], sum8);
      } else {
        #pragma unroll
        for (int j = 0; j < 8; ++j) vals[j] = 0.0f;
      }
      short8 sv;
      #pragma unroll
      for (int j = 0; j < 8; ++j) sv[j] = (short)f2bf(vals[j]);
      *(short8*)&ldsA[row * LDS_K + g * 8] = sv;
    }
    // stage W tile: 160 rows x 128 k (rows 0..95 = W_base, 96..159 = lora_A)
    #pragma unroll
    for (int it = 0; it < 10; ++it) {
      int idx = it * 256 + tid;
      int row = idx >> 4;
      int g = idx & 15;
      const float* rowp = (row < OUT_DIM) ? (W_base + (size_t)row * K_TOTAL)
                                          : (lora_A + (size_t)(row - OUT_DIM) * K_TOTAL);
      const floatx4* s4 = (const floatx4*)(rowp + kc + g * 8);
      floatx4 v0 = s4[0], v1 = s4[1];
      short8 sv;
      sv[0] = (short)f2bf(v0[0]); sv[1] = (short)f2bf(v0[1]);
      sv[2] = (short)f2bf(v0[2]); sv[3] = (short)f2bf(v0[3]);
      sv[4] = (short)f2bf(v1[0]); sv[5] = (short)f2bf(v1[1]);
      sv[6] = (short)f2bf(v1[2]); sv[7] = (short)f2bf(v1[3]);
      *(short8*)&ldsW[row * LDS_K + g * 8] = sv;
    }
    __syncthreads();
    // MFMA: wave handles rows [wave*16, wave*16+16), all 160 cols
    #pragma unroll
    for (int ks = 0; ks < 4; ++ks) {
      const int ko = ks * 32 + quad * 8;
      short8 a = *(const short8*)&ldsA[(wave * 16 + l16) * LDS_K + ko];
      #pragma unroll
      for (int nt = 0; nt < 10; ++nt) {
        short8 b = *(const short8*)&ldsW[(nt * 16 + l16) * LDS_K + ko];
        acc[nt] = __builtin_amdgcn_mfma_f32_16x16x32_bf16(a, b, acc[nt], 0, 0, 0);
      }
    }
  }
  // split-K accumulate (D layout: col=lane&15, row=quad*4+reg)
  #pragma unroll
  for (int nt = 0; nt < 10; ++nt) {
    #pragma unroll
    for (int r = 0; r < 4; ++r) {
      int m = m0 + wave * 16 + quad * 4 + r;
      int n = nt * 16 + l16;
      if (m < M_TOTAL) atomicAdd(&S[(size_t)m * N_TOTAL + n], acc[nt][r]);
    }
  }
  // pooled partials -> global (80 atomics/block; zero slots add 0 harmlessly)
  if (tid < 80) {
    int b = b_first + (tid >> 4);
    int d = d_first + (tid & 15);
    if (b < B_DIM)
      atomicAdd(&pooled[b * D_DIM + d], lds_pool[tid] * POOL_SCALE);
  }
}

// ---------------- router: MLP + softmax + top-2 ------------------------------
__global__ __launch_bounds__(256)
void router_kernel(const float* __restrict__ pooled, const float* __restrict__ W1,
                   const float* __restrict__ b1, const float* __restrict__ W2,
                   const float* __restrict__ b2, float* __restrict__ wfull,
                   float* __restrict__ probs_out) {
  __shared__ float sp[D_DIM];
  __shared__ float sh[H_DIM];
  __shared__ float slog[E_DIM];
  const int b = blockIdx.x;
  const int t = threadIdx.x;
  sp[t] = pooled[b * D_DIM + t];
  sp[t + 256] = pooled[b * D_DIM + t + 256];
  __syncthreads();
  float acc = b1[t];
  const float* w1r = W1 + (size_t)t * D_DIM;
  for (int d = 0; d < D_DIM; ++d) acc += sp[d] * w1r[d];
  sh[t] = fmaxf(acc, 0.0f);
  __syncthreads();
  if (t < E_DIM) {
    float a = b2[t];
    const float* w2r = W2 + t * H_DIM;
    for (int j = 0; j < H_DIM; ++j) a += sh[j] * w2r[j];
    slog[t] = a;
  }
  __syncthreads();
  if (t == 0) {
    float p[E_DIM];
    float mx = slog[0];
    for (int e = 1; e < E_DIM; ++e) mx = fmaxf(mx, slog[e]);
    float se = 0.0f;
    for (int e = 0; e < E_DIM; ++e) { p[e] = __expf(slog[e] - mx); se += p[e]; }
    float inv = 1.0f / se;
    for (int e = 0; e < E_DIM; ++e) { p[e] *= inv; probs_out[b * E_DIM + e] = p[e]; }
    // top-2, lowest index wins ties (strict > keeps earlier index)
    int i0 = 0;
    for (int e = 1; e < E_DIM; ++e) if (p[e] > p[i0]) i0 = e;
    int i1 = (i0 == 0) ? 1 : 0;
    for (int e = 0; e < E_DIM; ++e) if (e != i0 && p[e] > p[i1]) i1 = e;
    float s2 = p[i0] + p[i1];
    float invs = 1.0f / fmaxf(s2, 1e-6f);
    for (int e = 0; e < E_DIM; ++e) {
      float w = 0.0f;
      if (e == i0) w += p[i0] * invs;
      if (e == i1) w += p[i1] * invs;
      wfull[b * E_DIM + e] = w;
    }
  }
}

// ---------------- combine: out = S_base + b_base + 2*sum_e w*(S_lora.lora_B) -
__global__ __launch_bounds__(256)
void combine_kernel(const float* __restrict__ S, const float* __restrict__ b_base,
                    const float* __restrict__ lora_B, const float* __restrict__ wfull,
                    float* __restrict__ out) {
  int idx = blockIdx.x * 256 + threadIdx.x;
  if (idx >= M_TOTAL * OUT_DIM) return;
  int bv = idx / OUT_DIM;
  int o = idx - bv * OUT_DIM;
  int b = bv / V_DIM;
  const float* srow = S + (size_t)bv * N_TOTAL;
  float base = srow[o] + b_base[o];
  float moe = 0.0f;
  #pragma unroll
  for (int e = 0; e < E_DIM; ++e) {
    float we = wfull[b * E_DIM + e];
    if (we != 0.0f) {
      const float* lb = lora_B + ((size_t)e * OUT_DIM + o) * R_DIM;
      const float* tr = srow + OUT_DIM + e * R_DIM;
      float d = 0.0f;
      #pragma unroll
      for (int r = 0; r < R_DIM; ++r) d += tr[r] * lb[r];
      moe += we * d;
    }
  }
  out[idx] = base + SCALING * moe;
}

extern "C" void kernel_launch(void* const* d_in, const int* in_sizes, int n_in,
                              void* d_out, int out_size, void* d_ws, size_t ws_size,
                              hipStream_t stream) {
  const float* x      = (const float*)d_in[0];
  const float* W_base = (const float*)d_in[1];
  const float* b_base = (const float*)d_in[2];
  const float* W1     = (const float*)d_in[3];
  const float* b1     = (const float*)d_in[4];
  const float* W2     = (const float*)d_in[5];
  const float* b2     = (const float*)d_in[6];
  const float* lora_A = (const float*)d_in[7];
  const float* lora_B = (const float*)d_in[8];
  float* out = (float*)d_out;

  // workspace layout (floats): pooled[16384] | S[672*160] | wfull[256]
  float* ws     = (float*)d_ws;
  float* pooled = ws;
  float* S      = ws + 16384;
  float* wfull  = ws + 16384 + (size_t)M_TOTAL * N_TOTAL;

  // zero pooled + S (harness poisons ws with 0xAA every launch)
  hipMemsetAsync(d_ws, 0, (16384 + (size_t)M_TOTAL * N_TOTAL) * sizeof(float), stream);

  gemm_kernel<<<dim3(11, KSPLIT), 256, 0, stream>>>(x, W_base, lora_A, S, pooled);
  router_kernel<<<B_DIM, 256, 0, stream>>>(pooled, W1, b1, W2, b2, wfull,
                                           out + (size_t)M_TOTAL * OUT_DIM);
  combine_kernel<<<(M_TOTAL * OUT_DIM + 255) / 256, 256, 0, stream>>>(
      S, b_base, lora_B, wfull, out);
}

// Round 3
// 217.510 us; speedup vs baseline: 1.0286x; 1.0113x over previous
//
#include <hip/hip_runtime.h>

// Problem constants
#define B_DIM 32
#define V_DIM 21
#define D_DIM 512
#define P_DIM 64
#define M_TOTAL 672          // B*V
#define K_TOTAL 32768        // D*P
#define OUT_DIM 96
#define E_DIM 8
#define R_DIM 8
#define H_DIM 256
#define N_TOTAL 160          // OUT_DIM + E*R
#define SCALING 2.0f
#define POOL_SCALE (1.0f / (V_DIM * (float)P_DIM))

// GEMM tiling
#define BM 64
#define BK 128
#define KSPLIT 64
#define K_PER_BLOCK (K_TOTAL / KSPLIT)   // 512
#define CHUNKS (K_PER_BLOCK / BK)        // 4
#define LDS_K (BK + 8)                   // +16B pad: 2-way bank alias (free)

typedef __attribute__((ext_vector_type(4))) float floatx4;
typedef __attribute__((ext_vector_type(8))) short short8;

__device__ __forceinline__ unsigned short f2bf(float f) {
  union { float f; unsigned int u; } v; v.f = f;
  unsigned int u = v.u + (0x7FFFu + ((v.u >> 16) & 1u));  // RNE
  return (unsigned short)(u >> 16);
}

// ---------------- W pre-convert: [W_base|lora_A] fp32 -> bf16 Wb[160][32768] -
__global__ __launch_bounds__(256)
void convW_kernel(const float* __restrict__ W_base, const float* __restrict__ lora_A,
                  short* __restrict__ Wb) {
  size_t base = ((size_t)blockIdx.x * 256 + threadIdx.x) * 8;  // 5.24M shorts total
  int row = (int)(base >> 15);
  int k = (int)(base & 32767);
  const float* src = (row < OUT_DIM) ? (W_base + ((size_t)row << 15) + k)
                                     : (lora_A + ((size_t)(row - OUT_DIM) << 15) + k);
  floatx4 v0 = ((const floatx4*)src)[0];
  floatx4 v1 = ((const floatx4*)src)[1];
  short8 sv;
  sv[0] = (short)f2bf(v0[0]); sv[1] = (short)f2bf(v0[1]);
  sv[2] = (short)f2bf(v0[2]); sv[3] = (short)f2bf(v0[3]);
  sv[4] = (short)f2bf(v1[0]); sv[5] = (short)f2bf(v1[1]);
  sv[6] = (short)f2bf(v1[2]); sv[7] = (short)f2bf(v1[3]);
  *(short8*)(Wb + base) = sv;
}

// ---------------- fused base+LoRA GEMM + router pooling ----------------------
// S[672,160] += flat @ Wb^T ; pooled[b,d] += partial sums of x (pre-scaled)
__global__ __launch_bounds__(256, 2)
void gemm_kernel(const float* __restrict__ x, const short* __restrict__ Wb,
                 float* __restrict__ S, float* __restrict__ pooled) {
  __shared__ short ldsA[BM * LDS_K];      // 17,408 B
  __shared__ short ldsW[N_TOTAL * LDS_K]; // 43,520 B
  __shared__ float lds_pool[5 * 8];       // [b_local][d_local] fp32 partial sums
  const int tid = threadIdx.x;
  const int m0 = blockIdx.x * BM;
  const int kbase = blockIdx.y * K_PER_BLOCK;
  const int lane = tid & 63;
  const int wave = tid >> 6;
  const int quad = lane >> 4;
  const int l16 = lane & 15;
  const int mhalf = (wave & 1) * 32;      // wave's m-offset within tile
  const int nhalf = (wave >> 1) * 80;     // wave's n-offset
  const int b_first = m0 / V_DIM;
  const int d_first = kbase >> 6;         // k = d*64 + p

  if (tid < 40) lds_pool[tid] = 0.0f;

  floatx4 acc[2][5];
  #pragma unroll
  for (int mt = 0; mt < 2; ++mt)
    #pragma unroll
    for (int nt = 0; nt < 5; ++nt) acc[mt][nt] = (floatx4)(0.0f);

  // per-thread staging coords (fixed across chunks)
  const int a_row0 = tid >> 4;            // + it*16
  const int a_g = tid & 15;

  floatx4 pa[8];   // A prefetch: 4 its x 2 float4
  short8  pw[10];  // W prefetch: 10 its x 16B

#define ISSUE_LOADS(c)                                                          \
  {                                                                             \
    const int kc = kbase + (c) * BK;                                            \
    _Pragma("unroll")                                                           \
    for (int it = 0; it < 4; ++it) {                                            \
      int row = a_row0 + it * 16;                                               \
      int m = m0 + row;                                                         \
      if (m < M_TOTAL) {                                                        \
        const floatx4* s4 = (const floatx4*)(x + (size_t)m * K_TOTAL + kc + a_g * 8); \
        pa[it * 2] = s4[0];                                                     \
        pa[it * 2 + 1] = s4[1];                                                 \
      } else {                                                                  \
        pa[it * 2] = (floatx4)(0.0f);                                           \
        pa[it * 2 + 1] = (floatx4)(0.0f);                                       \
      }                                                                         \
    }                                                                           \
    _Pragma("unroll")                                                           \
    for (int it = 0; it < 10; ++it) {                                           \
      int idx = it * 256 + tid;                                                 \
      int row = idx >> 4;                                                       \
      int g = idx & 15;                                                         \
      pw[it] = *(const short8*)(Wb + (size_t)row * K_TOTAL + kc + g * 8);       \
    }                                                                           \
  }

#define CONVERT_WRITE(c)                                                        \
  {                                                                             \
    const int kc = kbase + (c) * BK;                                            \
    _Pragma("unroll")                                                           \
    for (int it = 0; it < 4; ++it) {                                            \
      int row = a_row0 + it * 16;                                               \
      int m = m0 + row;                                                         \
      floatx4 v0 = pa[it * 2], v1 = pa[it * 2 + 1];                             \
      if (m < M_TOTAL) {                                                        \
        float sum8 = ((v0[0] + v0[1]) + (v0[2] + v0[3])) +                      \
                     ((v1[0] + v1[1]) + (v1[2] + v1[3]));                       \
        int b_local = (m / V_DIM) - b_first;                                    \
        int d_local = ((kc + a_g * 8) >> 6) - d_first;                          \
        atomicAdd(&lds_pool[b_local * 8 + d_local], sum8);                      \
      }                                                                         \
      short8 sv;                                                                \
      sv[0] = (short)f2bf(v0[0]); sv[1] = (short)f2bf(v0[1]);                   \
      sv[2] = (short)f2bf(v0[2]); sv[3] = (short)f2bf(v0[3]);                   \
      sv[4] = (short)f2bf(v1[0]); sv[5] = (short)f2bf(v1[1]);                   \
      sv[6] = (short)f2bf(v1[2]); sv[7] = (short)f2bf(v1[3]);                   \
      *(short8*)&ldsA[row * LDS_K + a_g * 8] = sv;                              \
    }                                                                           \
    _Pragma("unroll")                                                           \
    for (int it = 0; it < 10; ++it) {                                           \
      int idx = it * 256 + tid;                                                 \
      int row = idx >> 4;                                                       \
      int g = idx & 15;                                                         \
      *(short8*)&ldsW[row * LDS_K + g * 8] = pw[it];                            \
    }                                                                           \
  }

  ISSUE_LOADS(0);
  __syncthreads();          // lds_pool zeros visible before first atomicAdd
  CONVERT_WRITE(0);

  for (int c = 0; c < CHUNKS; ++c) {
    __syncthreads();        // tiles (chunk c) ready
    if (c + 1 < CHUNKS) ISSUE_LOADS(c + 1);   // fly during MFMA phase
    #pragma unroll
    for (int ks = 0; ks < 4; ++ks) {
      const int ko = ks * 32 + quad * 8;
      short8 a0 = *(const short8*)&ldsA[(mhalf + l16) * LDS_K + ko];
      short8 a1 = *(const short8*)&ldsA[(mhalf + 16 + l16) * LDS_K + ko];
      #pragma unroll
      for (int nt = 0; nt < 5; ++nt) {
        short8 b = *(const short8*)&ldsW[(nhalf + nt * 16 + l16) * LDS_K + ko];
        acc[0][nt] = __builtin_amdgcn_mfma_f32_16x16x32_bf16(a0, b, acc[0][nt], 0, 0, 0);
        acc[1][nt] = __builtin_amdgcn_mfma_f32_16x16x32_bf16(a1, b, acc[1][nt], 0, 0, 0);
      }
    }
    __syncthreads();        // all LDS reads of chunk c done
    if (c + 1 < CHUNKS) CONVERT_WRITE(c + 1);
  }

  // split-K accumulate (D layout: col=lane&15, row=quad*4+reg)
  #pragma unroll
  for (int mt = 0; mt < 2; ++mt)
    #pragma unroll
    for (int nt = 0; nt < 5; ++nt)
      #pragma unroll
      for (int r = 0; r < 4; ++r) {
        int m = m0 + mhalf + mt * 16 + quad * 4 + r;
        int n = nhalf + nt * 16 + l16;
        if (m < M_TOTAL) atomicAdd(&S[(size_t)m * N_TOTAL + n], acc[mt][nt][r]);
      }

  // pooled partials -> global (40 atomics/block)
  if (tid < 40) {
    int b = b_first + (tid >> 3);
    int d = d_first + (tid & 7);
    if (b < B_DIM)
      atomicAdd(&pooled[b * D_DIM + d], lds_pool[tid] * POOL_SCALE);
  }
}

// ---------------- router: MLP + softmax + top-2 ------------------------------
__global__ __launch_bounds__(256)
void router_kernel(const float* __restrict__ pooled, const float* __restrict__ W1,
                   const float* __restrict__ b1, const float* __restrict__ W2,
                   const float* __restrict__ b2, float* __restrict__ wfull,
                   float* __restrict__ probs_out) {
  __shared__ float sp[D_DIM];
  __shared__ float sh[H_DIM];
  __shared__ float slog[E_DIM];
  const int b = blockIdx.x;
  const int t = threadIdx.x;
  sp[t] = pooled[b * D_DIM + t];
  sp[t + 256] = pooled[b * D_DIM + t + 256];
  __syncthreads();
  float acc = b1[t];
  const float* w1r = W1 + (size_t)t * D_DIM;
  for (int d = 0; d < D_DIM; ++d) acc += sp[d] * w1r[d];
  sh[t] = fmaxf(acc, 0.0f);
  __syncthreads();
  if (t < E_DIM) {
    float a = b2[t];
    const float* w2r = W2 + t * H_DIM;
    for (int j = 0; j < H_DIM; ++j) a += sh[j] * w2r[j];
    slog[t] = a;
  }
  __syncthreads();
  if (t == 0) {
    float p[E_DIM];
    float mx = slog[0];
    for (int e = 1; e < E_DIM; ++e) mx = fmaxf(mx, slog[e]);
    float se = 0.0f;
    for (int e = 0; e < E_DIM; ++e) { p[e] = __expf(slog[e] - mx); se += p[e]; }
    float inv = 1.0f / se;
    for (int e = 0; e < E_DIM; ++e) { p[e] *= inv; probs_out[b * E_DIM + e] = p[e]; }
    // top-2, lowest index wins ties (strict > keeps earlier index)
    int i0 = 0;
    for (int e = 1; e < E_DIM; ++e) if (p[e] > p[i0]) i0 = e;
    int i1 = (i0 == 0) ? 1 : 0;
    for (int e = 0; e < E_DIM; ++e) if (e != i0 && p[e] > p[i1]) i1 = e;
    float s2 = p[i0] + p[i1];
    float invs = 1.0f / fmaxf(s2, 1e-6f);
    for (int e = 0; e < E_DIM; ++e) {
      float w = 0.0f;
      if (e == i0) w += p[i0] * invs;
      if (e == i1) w += p[i1] * invs;
      wfull[b * E_DIM + e] = w;
    }
  }
}

// ---------------- combine: out = S_base + b_base + 2*sum_e w*(S_lora.lora_B) -
__global__ __launch_bounds__(256)
void combine_kernel(const float* __restrict__ S, const float* __restrict__ b_base,
                    const float* __restrict__ lora_B, const float* __restrict__ wfull,
                    float* __restrict__ out) {
  int idx = blockIdx.x * 256 + threadIdx.x;
  if (idx >= M_TOTAL * OUT_DIM) return;
  int bv = idx / OUT_DIM;
  int o = idx - bv * OUT_DIM;
  int b = bv / V_DIM;
  const float* srow = S + (size_t)bv * N_TOTAL;
  float base = srow[o] + b_base[o];
  float moe = 0.0f;
  #pragma unroll
  for (int e = 0; e < E_DIM; ++e) {
    float we = wfull[b * E_DIM + e];
    if (we != 0.0f) {
      const float* lb = lora_B + ((size_t)e * OUT_DIM + o) * R_DIM;
      const float* tr = srow + OUT_DIM + e * R_DIM;
      float d = 0.0f;
      #pragma unroll
      for (int r = 0; r < R_DIM; ++r) d += tr[r] * lb[r];
      moe += we * d;
    }
  }
  out[idx] = base + SCALING * moe;
}

extern "C" void kernel_launch(void* const* d_in, const int* in_sizes, int n_in,
                              void* d_out, int out_size, void* d_ws, size_t ws_size,
                              hipStream_t stream) {
  const float* x      = (const float*)d_in[0];
  const float* W_base = (const float*)d_in[1];
  const float* b_base = (const float*)d_in[2];
  const float* W1     = (const float*)d_in[3];
  const float* b1     = (const float*)d_in[4];
  const float* W2     = (const float*)d_in[5];
  const float* b2     = (const float*)d_in[6];
  const float* lora_A = (const float*)d_in[7];
  const float* lora_B = (const float*)d_in[8];
  float* out = (float*)d_out;

  // ws layout (floats): pooled[16384] | S[107520] | wfull[256] | Wb[2.62M fl]
  float* ws     = (float*)d_ws;
  float* pooled = ws;
  float* S      = ws + 16384;
  float* wfull  = ws + 16384 + (size_t)M_TOTAL * N_TOTAL;
  short* Wb     = (short*)(wfull + 256);

  // zero pooled + S (harness poisons ws with 0xAA every launch)
  hipMemsetAsync(d_ws, 0, (16384 + (size_t)M_TOTAL * N_TOTAL) * sizeof(float), stream);

  convW_kernel<<<(N_TOTAL * K_TOTAL / 8 + 255) / 256, 256, 0, stream>>>(W_base, lora_A, Wb);
  gemm_kernel<<<dim3(11, KSPLIT), 256, 0, stream>>>(x, Wb, S, pooled);
  router_kernel<<<B_DIM, 256, 0, stream>>>(pooled, W1, b1, W2, b2, wfull,
                                           out + (size_t)M_TOTAL * OUT_DIM);
  combine_kernel<<<(M_TOTAL * OUT_DIM + 255) / 256, 256, 0, stream>>>(
      S, b_base, lora_B, wfull, out);
}